// Round 5
// baseline (999.390 us; speedup 1.0000x reference)
//
#include <hip/hip_runtime.h>
#include <hip/hip_bf16.h>

#define B_   256
#define T_   512
#define H_   128
#define G3_  384

// ---- tiled GEMM config ----
#define TM   128
#define TN   128
#define TK   32
#define LDA  132

typedef float v4f __attribute__((ext_vector_type(4)));

// Raw v_rcp_f32 (~1 ulp) — avoids the IEEE v_div_scale/fmas/fixup sequence.
__device__ __forceinline__ float fast_rcp(float x) {
    return __builtin_amdgcn_rcpf(x);
}
__device__ __forceinline__ float sigmoid_f(float x) {
    return fast_rcp(1.0f + __expf(-x));
}
__device__ __forceinline__ float tanh_f(float x) {
    return fmaf(-2.0f, fast_rcp(__expf(2.0f * x) + 1.0f), 1.0f);
}

// Butterfly sum over each aligned 8-lane group, pure DPP (no LDS pipe),
// result valid on ALL lanes: quad_perm xor1, quad_perm xor2, row_half_mirror.
// (Correctness-proven in the R8-era kernel.)
__device__ __forceinline__ float bfly_fold8(float v) {
    int x;
    x = __builtin_amdgcn_update_dpp(0, __float_as_int(v), 0x0B1, 0xF, 0xF, true);
    v += __int_as_float(x);   // xor 1
    x = __builtin_amdgcn_update_dpp(0, __float_as_int(v), 0x04E, 0xF, 0xF, true);
    v += __int_as_float(x);   // xor 2
    x = __builtin_amdgcn_update_dpp(0, __float_as_int(v), 0x141, 0xF, 0xF, true);
    v += __int_as_float(x);   // other quad (half mirror)
    return v;
}

#define DOT4(acc, hv, wv)                                        \
    acc = fmaf((hv).x, (wv).x, acc);                             \
    acc = fmaf((hv).y, (wv).y, acc);                             \
    acc = fmaf((hv).z, (wv).z, acc);                             \
    acc = fmaf((hv).w, (wv).w, acc);

// ---------------------------------------------------------------------------
// gx GEMM (unchanged from R2 — ~150 us, healthy)
// ---------------------------------------------------------------------------
template<bool GATHER>
__global__ __launch_bounds__(256, 2)
void gx_gemm(const float* __restrict__ X,
             const int*   __restrict__ idx,
             const float* __restrict__ emb,
             const float* __restrict__ W,     // [384,128] row-major
             const float* __restrict__ bias,  // [384]
             float*       __restrict__ gx)    // [M,384]
{
    __shared__ __align__(16) float As[2][TK][LDA];
    __shared__ __align__(16) float Bs[2][TK][LDA];

    const int tid = threadIdx.x;
    const int tn  = tid & 15;
    const int tm  = tid >> 4;
    const int n0  = blockIdx.x * TN;
    const int m0  = blockIdx.y * TM;

    const int q  = tid & 7;
    const float* rowA[4];
    const float* rowB[4];
#pragma unroll
    for (int s = 0; s < 4; s++) {
        const int r = (tid >> 3) + 32 * s;
        rowA[s] = GATHER ? (emb + (size_t)idx[m0 + r] * H_)
                         : (X + (size_t)(m0 + r) * H_);
        rowB[s] = W + (size_t)(n0 + r) * H_;
    }

    float4 stA[4], stB[4];
    auto load_chunk = [&](int kc) {
#pragma unroll
        for (int s = 0; s < 4; s++) {
            stA[s] = *(const float4*)(rowA[s] + kc + q * 4);
            stB[s] = *(const float4*)(rowB[s] + kc + q * 4);
        }
    };
    auto store_chunk = [&](int buf) {
#pragma unroll
        for (int s = 0; s < 4; s++) {
            const int r = (tid >> 3) + 32 * s;
#pragma unroll
            for (int d = 0; d < 4; d++) {
                As[buf][q * 4 + d][r] = ((const float*)&stA[s])[d];
                Bs[buf][q * 4 + d][r] = ((const float*)&stB[s])[d];
            }
        }
    };

    float4 acc[2][2][4];
#pragma unroll
    for (int a = 0; a < 2; a++)
#pragma unroll
        for (int b = 0; b < 2; b++)
#pragma unroll
            for (int c = 0; c < 4; c++) acc[a][b][c] = make_float4(0.f, 0.f, 0.f, 0.f);

    load_chunk(0);
    store_chunk(0);
    __syncthreads();

    for (int c = 0; c < 4; c++) {
        if (c < 3) load_chunk((c + 1) * TK);
        const int buf = c & 1;
#pragma unroll 4
        for (int k = 0; k < TK; k++) {
            float4 a0 = *(const float4*)&As[buf][k][tm * 4];
            float4 a1 = *(const float4*)&As[buf][k][64 + tm * 4];
            float4 b0 = *(const float4*)&Bs[buf][k][tn * 4];
            float4 b1 = *(const float4*)&Bs[buf][k][64 + tn * 4];
            float4 av[2] = {a0, a1}, bv[2] = {b0, b1};
#pragma unroll
            for (int mg = 0; mg < 2; mg++)
#pragma unroll
                for (int mi = 0; mi < 4; mi++) {
                    const float am = ((const float*)&av[mg])[mi];
#pragma unroll
                    for (int ng = 0; ng < 2; ng++) {
                        acc[mg][ng][mi].x = fmaf(am, bv[ng].x, acc[mg][ng][mi].x);
                        acc[mg][ng][mi].y = fmaf(am, bv[ng].y, acc[mg][ng][mi].y);
                        acc[mg][ng][mi].z = fmaf(am, bv[ng].z, acc[mg][ng][mi].z);
                        acc[mg][ng][mi].w = fmaf(am, bv[ng].w, acc[mg][ng][mi].w);
                    }
                }
        }
        if (c < 3) {
            store_chunk(buf ^ 1);
            __syncthreads();
        }
    }

    const float4 bb0 = *(const float4*)(bias + n0 + tn * 4);
    const float4 bb1 = *(const float4*)(bias + n0 + 64 + tn * 4);
#pragma unroll
    for (int mg = 0; mg < 2; mg++)
#pragma unroll
        for (int mi = 0; mi < 4; mi++) {
            const int m = m0 + mg * 64 + tm * 4 + mi;
            float* dst = gx + (size_t)m * G3_ + n0;
            float4 v0 = acc[mg][0][mi];
            v0.x += bb0.x; v0.y += bb0.y; v0.z += bb0.z; v0.w += bb0.w;
            float4 v1 = acc[mg][1][mi];
            v1.x += bb1.x; v1.y += bb1.y; v1.z += bb1.z; v1.w += bb1.w;
            *(float4*)(dst + tn * 4) = v0;
            *(float4*)(dst + 64 + tn * 4) = v1;
        }
}

// ---------------------------------------------------------------------------
// GRU recurrence — R13: 2 units per thread (U=2), K-split 8.
//
// 512 threads/block, one block per batch row. Thread (jg2 = tid>>3, ks =
// tid&7) owns hidden units j0 = 2*jg2 and j0+1, cols ks*16..+15 (6 rows x 16
// = 96 W floats/thread, same as R12).
//
// Why: LDS h-read traffic = 64KB/U per step (invariant in the K-split!).
// R12's U=1 read 64 KB/CU/step (~550-770 cyc of the CU-shared LDS pipe =
// 57% occupied, co-bottleneck with VALU at 83%). U=2 halves it to 32 KB
// (4 x ds_read_b128/thread), shares each h-read across 2 units' dots, and
// pairs the gx-prefetch / bias / h / hseq accesses as float2.
//
// Bank conflicts with LINEAR h2 layout: lane reads float4 blocks of its
// 16-float chunk in ROTATED order f = (c + ks/2) & 3. For each read slot c,
// the 8 ks-groups then cover all 32 banks (even ks -> banks 0..15, odd ->
// 16..31; the rotation de-aliases ks vs ks+4). W blocks are loaded in the
// same rotated order at init so h[f]*W[f] stays aligned. Writes (ks==0,
// ds_write_b64 at even word pairs 16w+2q) are conflict-free.
// ---------------------------------------------------------------------------
template<bool STORE_H, bool FINAL>
__global__ __launch_bounds__(512)
__attribute__((amdgpu_waves_per_eu(2, 2)))
void gru_rec(const float* __restrict__ gx,   // [B,T,384]
             const float* __restrict__ Whh,  // [384,128]
             const float* __restrict__ bhh,  // [384]
             float*       __restrict__ hseq, // [B,T,128] if STORE_H
             const float* __restrict__ fc_w, // [3,128]  if FINAL
             const float* __restrict__ fc_b, // [3]      if FINAL
             float*       __restrict__ out)  // [B,3]    if FINAL
{
    __shared__ __align__(16) float h2[2][H_];   // double-buffered h (linear)

    const int tid = threadIdx.x;
    const int b   = blockIdx.x;
    const int jg2 = tid >> 3;      // unit pair 0..63
    const int ks  = tid & 7;       // k-slice 0..7 (16 cols each)
    const int j0  = jg2 * 2;       // first owned unit
    const int rot = ks >> 1;       // read-order rotation (bank de-alias)

    // --- W fragment: rows {j0,j0+1} x {r,z,n}, cols ks*16..+15, blocks in
    // rotated order so W*[c] pairs with the slot-c h read ---
    v4f W0r[4], W0z[4], W0n[4], W1r[4], W1z[4], W1n[4];
    {
        const float* r0 = Whh + (size_t)(j0      ) * H_ + ks * 16;
        const float* z0 = Whh + (size_t)(j0 + 128) * H_ + ks * 16;
        const float* n0 = Whh + (size_t)(j0 + 256) * H_ + ks * 16;
#pragma unroll
        for (int c = 0; c < 4; c++) {
            const int f = ((c + rot) & 3) * 4;
            W0r[c] = *(const v4f*)(r0 + f);
            W0z[c] = *(const v4f*)(z0 + f);
            W0n[c] = *(const v4f*)(n0 + f);
            W1r[c] = *(const v4f*)(r0 + H_ + f);
            W1z[c] = *(const v4f*)(z0 + H_ + f);
            W1n[c] = *(const v4f*)(n0 + H_ + f);
        }
    }

    const float2 bhr = *(const float2*)(bhh + j0);
    const float2 bhz = *(const float2*)(bhh + j0 + H_);
    const float2 bhn = *(const float2*)(bhh + j0 + 2 * H_);

    const float* gxb = gx + (size_t)b * T_ * G3_;
    const float* gp  = gxb + j0;
    float2 gr = *(const float2*)(gp);
    float2 gz = *(const float2*)(gp + H_);
    float2 gn = *(const float2*)(gp + 2 * H_);
    gp += G3_;
    float2 h_old; h_old.x = 0.0f; h_old.y = 0.0f;

    if (tid < H_) h2[0][tid] = 0.0f;

    // rotated read offsets (words) into the linear 128-float h buffer
    const int ho0 = ks * 16 + (((0 + rot) & 3) << 2);
    const int ho1 = ks * 16 + (((1 + rot) & 3) << 2);
    const int ho2 = ks * 16 + (((2 + rot) & 3) << 2);
    const int ho3 = ks * 16 + (((3 + rot) & 3) << 2);

    float* hp = STORE_H ? (hseq + (size_t)b * T_ * H_ + j0) : nullptr;

    __syncthreads();

    // one-time residency hint for the W fragment (pre-loop only; the R12
    // in-loop variant was not separable from the rcp gain and is dropped)
    asm volatile("" : "+v"(W0r[0]), "+v"(W0r[1]), "+v"(W0r[2]), "+v"(W0r[3]),
                      "+v"(W0z[0]), "+v"(W0z[1]), "+v"(W0z[2]), "+v"(W0z[3]),
                      "+v"(W0n[0]), "+v"(W0n[1]), "+v"(W0n[2]), "+v"(W0n[3]),
                      "+v"(W1r[0]), "+v"(W1r[1]), "+v"(W1r[2]), "+v"(W1r[3]),
                      "+v"(W1z[0]), "+v"(W1z[1]), "+v"(W1z[2]), "+v"(W1z[3]),
                      "+v"(W1n[0]), "+v"(W1n[1]), "+v"(W1n[2]), "+v"(W1n[3]));

#define GRU_STEP(HIN, HOUT)                                                   \
    {                                                                         \
        const float2 gr2_ = *(const float2*)(gp);                             \
        const float2 gz2_ = *(const float2*)(gp + H_);                        \
        const float2 gn2_ = *(const float2*)(gp + 2 * H_);                    \
        gp += G3_;                                                            \
        float p0r = 0.f, p0z = 0.f, p0n = 0.f;                                \
        float p1r = 0.f, p1z = 0.f, p1n = 0.f;                                \
        {                                                                     \
            float4 hv;                                                        \
            hv = *(const float4*)&(HIN)[ho0];                                 \
            DOT4(p0r, hv, W0r[0]) DOT4(p0z, hv, W0z[0]) DOT4(p0n, hv, W0n[0])\
            DOT4(p1r, hv, W1r[0]) DOT4(p1z, hv, W1z[0]) DOT4(p1n, hv, W1n[0])\
            hv = *(const float4*)&(HIN)[ho1];                                 \
            DOT4(p0r, hv, W0r[1]) DOT4(p0z, hv, W0z[1]) DOT4(p0n, hv, W0n[1])\
            DOT4(p1r, hv, W1r[1]) DOT4(p1z, hv, W1z[1]) DOT4(p1n, hv, W1n[1])\
            hv = *(const float4*)&(HIN)[ho2];                                 \
            DOT4(p0r, hv, W0r[2]) DOT4(p0z, hv, W0z[2]) DOT4(p0n, hv, W0n[2])\
            DOT4(p1r, hv, W1r[2]) DOT4(p1z, hv, W1z[2]) DOT4(p1n, hv, W1n[2])\
            hv = *(const float4*)&(HIN)[ho3];                                 \
            DOT4(p0r, hv, W0r[3]) DOT4(p0z, hv, W0z[3]) DOT4(p0n, hv, W0n[3])\
            DOT4(p1r, hv, W1r[3]) DOT4(p1z, hv, W1z[3]) DOT4(p1n, hv, W1n[3])\
        }                                                                     \
        p0r = bfly_fold8(p0r); p0z = bfly_fold8(p0z); p0n = bfly_fold8(p0n);  \
        p1r = bfly_fold8(p1r); p1z = bfly_fold8(p1z); p1n = bfly_fold8(p1n);  \
        const float r0_ = sigmoid_f(gr.x + p0r + bhr.x);                      \
        const float z0_ = sigmoid_f(gz.x + p0z + bhz.x);                      \
        const float n0_ = tanh_f(gn.x + r0_ * (p0n + bhn.x));                 \
        h_old.x = (1.0f - z0_) * n0_ + z0_ * h_old.x;                         \
        const float r1_ = sigmoid_f(gr.y + p1r + bhr.y);                      \
        const float z1_ = sigmoid_f(gz.y + p1z + bhz.y);                      \
        const float n1_ = tanh_f(gn.y + r1_ * (p1n + bhn.y));                 \
        h_old.y = (1.0f - z1_) * n1_ + z1_ * h_old.y;                         \
        if (ks == 0) {                                                        \
            *(float2*)&(HOUT)[j0] = h_old;                                    \
            if (STORE_H) *(float2*)hp = h_old;                                \
        }                                                                     \
        if (STORE_H) hp += H_;                                                \
        gr = gr2_; gz = gz2_; gn = gn2_;                                      \
        __syncthreads();                                                      \
    }

    for (int t = 0; t < T_; t += 2) {
        GRU_STEP(h2[0], h2[1])
        GRU_STEP(h2[1], h2[0])
    }
#undef GRU_STEP

    if (FINAL) {
        // h2[1] is dead after the loop's trailing barrier — reuse linearly.
        if (ks == 0) {
            h2[1][j0]     = fmaxf(h_old.x, 0.0f);   // relu(last hidden)
            h2[1][j0 + 1] = fmaxf(h_old.y, 0.0f);
        }
        __syncthreads();
        if (tid < 3) {
            float acc = fc_b[tid];
            const float* fw = fc_w + tid * H_;
#pragma unroll
            for (int k = 0; k < H_; k++) acc = fmaf(h2[1][k], fw[k], acc);
            out[b * 3 + tid] = acc;
        }
    }
}

// ---------------------------------------------------------------------------
extern "C" void kernel_launch(void* const* d_in, const int* in_sizes, int n_in,
                              void* d_out, int out_size, void* d_ws, size_t ws_size,
                              hipStream_t stream)
{
    const int*   x    = (const int*)  d_in[0];
    const float* emb  = (const float*)d_in[1];
    const float* W_ih = (const float*)d_in[2];  // [2,384,128]
    const float* W_hh = (const float*)d_in[3];  // [2,384,128]
    const float* b_ih = (const float*)d_in[4];  // [2,384]
    const float* b_hh = (const float*)d_in[5];  // [2,384]
    const float* fc_w = (const float*)d_in[6];  // [3,128]
    const float* fc_b = (const float*)d_in[7];  // [3]
    float* out = (float*)d_out;

    const int M = B_ * T_;                                   // 131072 rows
    const size_t gx_f32 = (size_t)M * G3_ * sizeof(float);   // 201.3 MB

    float* gx = (float*)d_ws;
    float* h1 = (float*)((char*)d_ws + gx_f32);              // 67.1 MB

    dim3 ggx(G3_ / TN, M / TM);   // (3, 1024)
    dim3 bgx(256);
    dim3 grec(B_), brec(512);

    hipLaunchKernelGGL((gx_gemm<true>), ggx, bgx, 0, stream,
                       nullptr, x, emb, W_ih, b_ih, gx);
    hipLaunchKernelGGL((gru_rec<true, false>), grec, brec, 0, stream,
                       gx, W_hh, b_hh, h1, nullptr, nullptr, nullptr);
    hipLaunchKernelGGL((gx_gemm<false>), ggx, bgx, 0, stream,
                       h1, nullptr, nullptr, W_ih + G3_ * H_, b_ih + G3_, gx);
    hipLaunchKernelGGL((gru_rec<false, true>), grec, brec, 0, stream,
                       gx, W_hh + G3_ * H_, b_hh + G3_, nullptr, fc_w, fc_b, out);
}

// Round 7
// 917.086 us; speedup vs baseline: 1.0897x; 1.0897x over previous
//
#include <hip/hip_runtime.h>
#include <hip/hip_bf16.h>

#define B_   256
#define T_   512
#define H_   128
#define G3_  384

// ---- tiled GEMM config ----
#define TM   128
#define TN   128
#define TK   32
#define LDA  132

typedef float v4f __attribute__((ext_vector_type(4)));

// Raw v_rcp_f32 (~1 ulp) — avoids the IEEE v_div_scale/fmas/fixup sequence.
__device__ __forceinline__ float fast_rcp(float x) {
    return __builtin_amdgcn_rcpf(x);
}
__device__ __forceinline__ float sigmoid_f(float x) {
    return fast_rcp(1.0f + __expf(-x));
}
__device__ __forceinline__ float tanh_f(float x) {
    return fmaf(-2.0f, fast_rcp(__expf(2.0f * x) + 1.0f), 1.0f);
}

// Butterfly sum over each aligned 4-lane quad, pure DPP, result on ALL lanes.
__device__ __forceinline__ float bfly_fold4(float v) {
    int x;
    x = __builtin_amdgcn_update_dpp(0, __float_as_int(v), 0x0B1, 0xF, 0xF, true);
    v += __int_as_float(x);   // xor 1
    x = __builtin_amdgcn_update_dpp(0, __float_as_int(v), 0x04E, 0xF, 0xF, true);
    v += __int_as_float(x);   // xor 2
    return v;
}

// Two independent even/odd accumulators per gate: adjacent v_fmac_f32 pairs
// are SLP-merged into v_pk_fma_f32 on gfx950 (worst case: stays scalar =
// exactly the proven R12 code).
#define DOT4PK(accE, accO, hv, wv)                               \
    accE = fmaf((hv).x, (wv).x, accE);                           \
    accO = fmaf((hv).y, (wv).y, accO);                           \
    accE = fmaf((hv).z, (wv).z, accE);                           \
    accO = fmaf((hv).w, (wv).w, accO);

// ---------------------------------------------------------------------------
// gx GEMM (R2 structure; R14 adds bias2 fold for the r/z regions — moves the
// b_hh[r], b_hh[z] adds out of the serial recurrence loop)
// ---------------------------------------------------------------------------
template<bool GATHER>
__global__ __launch_bounds__(256, 2)
void gx_gemm(const float* __restrict__ X,
             const int*   __restrict__ idx,
             const float* __restrict__ emb,
             const float* __restrict__ W,     // [384,128] row-major
             const float* __restrict__ bias,  // [384]  (b_ih)
             const float* __restrict__ bias2, // [384]  (b_hh; only n<256 used)
             float*       __restrict__ gx)    // [M,384]
{
    __shared__ __align__(16) float As[2][TK][LDA];
    __shared__ __align__(16) float Bs[2][TK][LDA];

    const int tid = threadIdx.x;
    const int tn  = tid & 15;
    const int tm  = tid >> 4;
    const int n0  = blockIdx.x * TN;
    const int m0  = blockIdx.y * TM;

    const int q  = tid & 7;
    const float* rowA[4];
    const float* rowB[4];
#pragma unroll
    for (int s = 0; s < 4; s++) {
        const int r = (tid >> 3) + 32 * s;
        rowA[s] = GATHER ? (emb + (size_t)idx[m0 + r] * H_)
                         : (X + (size_t)(m0 + r) * H_);
        rowB[s] = W + (size_t)(n0 + r) * H_;
    }

    float4 stA[4], stB[4];
    auto load_chunk = [&](int kc) {
#pragma unroll
        for (int s = 0; s < 4; s++) {
            stA[s] = *(const float4*)(rowA[s] + kc + q * 4);
            stB[s] = *(const float4*)(rowB[s] + kc + q * 4);
        }
    };
    auto store_chunk = [&](int buf) {
#pragma unroll
        for (int s = 0; s < 4; s++) {
            const int r = (tid >> 3) + 32 * s;
#pragma unroll
            for (int d = 0; d < 4; d++) {
                As[buf][q * 4 + d][r] = ((const float*)&stA[s])[d];
                Bs[buf][q * 4 + d][r] = ((const float*)&stB[s])[d];
            }
        }
    };

    float4 acc[2][2][4];
#pragma unroll
    for (int a = 0; a < 2; a++)
#pragma unroll
        for (int b = 0; b < 2; b++)
#pragma unroll
            for (int c = 0; c < 4; c++) acc[a][b][c] = make_float4(0.f, 0.f, 0.f, 0.f);

    load_chunk(0);
    store_chunk(0);
    __syncthreads();

    for (int c = 0; c < 4; c++) {
        if (c < 3) load_chunk((c + 1) * TK);
        const int buf = c & 1;
#pragma unroll 4
        for (int k = 0; k < TK; k++) {
            float4 a0 = *(const float4*)&As[buf][k][tm * 4];
            float4 a1 = *(const float4*)&As[buf][k][64 + tm * 4];
            float4 b0 = *(const float4*)&Bs[buf][k][tn * 4];
            float4 b1 = *(const float4*)&Bs[buf][k][64 + tn * 4];
            float4 av[2] = {a0, a1}, bv[2] = {b0, b1};
#pragma unroll
            for (int mg = 0; mg < 2; mg++)
#pragma unroll
                for (int mi = 0; mi < 4; mi++) {
                    const float am = ((const float*)&av[mg])[mi];
#pragma unroll
                    for (int ng = 0; ng < 2; ng++) {
                        acc[mg][ng][mi].x = fmaf(am, bv[ng].x, acc[mg][ng][mi].x);
                        acc[mg][ng][mi].y = fmaf(am, bv[ng].y, acc[mg][ng][mi].y);
                        acc[mg][ng][mi].z = fmaf(am, bv[ng].z, acc[mg][ng][mi].z);
                        acc[mg][ng][mi].w = fmaf(am, bv[ng].w, acc[mg][ng][mi].w);
                    }
                }
        }
        if (c < 3) {
            store_chunk(buf ^ 1);
            __syncthreads();
        }
    }

    float4 bb0 = *(const float4*)(bias + n0 + tn * 4);
    float4 bb1 = *(const float4*)(bias + n0 + 64 + tn * 4);
    if (n0 < 2 * H_) {   // r/z gate regions: fold hidden bias in here (uniform)
        const float4 c0 = *(const float4*)(bias2 + n0 + tn * 4);
        const float4 c1 = *(const float4*)(bias2 + n0 + 64 + tn * 4);
        bb0.x += c0.x; bb0.y += c0.y; bb0.z += c0.z; bb0.w += c0.w;
        bb1.x += c1.x; bb1.y += c1.y; bb1.z += c1.z; bb1.w += c1.w;
    }
#pragma unroll
    for (int mg = 0; mg < 2; mg++)
#pragma unroll
        for (int mi = 0; mi < 4; mi++) {
            const int m = m0 + mg * 64 + tm * 4 + mi;
            float* dst = gx + (size_t)m * G3_ + n0;
            float4 v0 = acc[mg][0][mi];
            v0.x += bb0.x; v0.y += bb0.y; v0.z += bb0.z; v0.w += bb0.w;
            float4 v1 = acc[mg][1][mi];
            v1.x += bb1.x; v1.y += bb1.y; v1.z += bb1.z; v1.w += bb1.w;
            *(float4*)(dst + tn * 4) = v0;
            *(float4*)(dst + 64 + tn * 4) = v1;
        }
}

// ---------------------------------------------------------------------------
// GRU recurrence — R14 (resubmit after infra failure): R12 structure (U=1,
// K=4 — best measured, 286us) with even/odd-paired dot accumulators.
//
// R13 post-mortem established dur ∝ VALU inst count/thread (U=2 halved LDS
// traffic yet regressed +31% = exactly its +31% inst count). R14 cuts the
// inst count on the R12 structure:
//   - even/odd accumulator pairs per gate: adjacent independent v_fmac pairs
//     SLP-merge into v_pk_fma_f32 (96 fmac -> ~48 pk_fma + 3 hadds).
//   - b_hh for r,z folded into the gx GEMM bias (bhn must stay: it sits
//     inside r*(p_n + bhn)).
//   - h_new = fmaf(z, h_old - n, n)  (1 op fewer than (1-z)*n + z*h).
//
// Thread (jg = tid>>2, ks = tid&3) owns unit jg, cols ks*32..+31.
// h2 swizzle: h[j] at word sw(j)=16*((j>>2)&7)+4*(j>>5)+(j&3); read offsets
// 16c+4ks are 4 distinct bank quads x 16-lane broadcast — conflict-free
// (measured 0 in R12).
// ---------------------------------------------------------------------------
template<bool STORE_H, bool FINAL>
__global__ __launch_bounds__(512)
__attribute__((amdgpu_waves_per_eu(2, 2)))
void gru_rec(const float* __restrict__ gx,   // [B,T,384] (r,z include b_hh)
             const float* __restrict__ Whh,  // [384,128]
             const float* __restrict__ bhh,  // [384]
             float*       __restrict__ hseq, // [B,T,128] if STORE_H
             const float* __restrict__ fc_w, // [3,128]  if FINAL
             const float* __restrict__ fc_b, // [3]      if FINAL
             float*       __restrict__ out)  // [B,3]    if FINAL
{
    __shared__ __align__(16) float h2[2][H_];   // double-buffered swizzled h

    const int tid = threadIdx.x;
    const int b   = blockIdx.x;
    const int jg  = tid >> 2;      // hidden unit 0..127
    const int ks  = tid & 3;       // k-slice 0..3 (32 cols each)

    // --- W_hh fragment: rows jg / jg+128 / jg+256, cols ks*32..+31 ---
    const v4f* wr = (const v4f*)(Whh + (size_t)(jg      ) * H_ + ks * 32);
    const v4f* wz = (const v4f*)(Whh + (size_t)(jg + 128) * H_ + ks * 32);
    const v4f* wn = (const v4f*)(Whh + (size_t)(jg + 256) * H_ + ks * 32);
    v4f Wr[8], Wz[8], Wn[8];
#pragma unroll
    for (int c = 0; c < 8; c++) { Wr[c] = wr[c]; Wz[c] = wz[c]; Wn[c] = wn[c]; }

    const float bhn = bhh[jg + 2 * H_];   // r,z biases are folded into gx

    const float* gxb = gx + (size_t)b * T_ * G3_;
    float gr = gxb[jg], gz = gxb[jg + 128], gn = gxb[jg + 256];
    float h_old = 0.0f;

    if (tid < H_) h2[0][tid] = 0.0f;   // zeros are swizzle-invariant

    // write word for this unit: sw(jg)
    const int hw = ((jg >> 2) & 7) * 16 + (jg >> 5) * 4 + (jg & 3);
    const int hb = ks * 4;             // read base within each 16-word chunk

    // walked pointers (strength-reduced; no per-step mul / clamp)
    const float* gnx = gxb + G3_;
    float* hp = STORE_H ? (hseq + (size_t)b * T_ * H_ + jg) : nullptr;

    __syncthreads();

    // one-time residency hint for the W fragment
    asm volatile("" : "+v"(Wr[0]), "+v"(Wr[1]), "+v"(Wr[2]), "+v"(Wr[3]),
                      "+v"(Wr[4]), "+v"(Wr[5]), "+v"(Wr[6]), "+v"(Wr[7]),
                      "+v"(Wz[0]), "+v"(Wz[1]), "+v"(Wz[2]), "+v"(Wz[3]),
                      "+v"(Wz[4]), "+v"(Wz[5]), "+v"(Wz[6]), "+v"(Wz[7]),
                      "+v"(Wn[0]), "+v"(Wn[1]), "+v"(Wn[2]), "+v"(Wn[3]),
                      "+v"(Wn[4]), "+v"(Wn[5]), "+v"(Wn[6]), "+v"(Wn[7]));

#define GRU_STEP(HIN, HOUT)                                                   \
    {                                                                         \
        const float gr2_ = gnx[jg];                                           \
        const float gz2_ = gnx[jg + 128];                                     \
        const float gn2_ = gnx[jg + 256];                                     \
        gnx += G3_;                                                           \
        float prE = 0.f, prO = 0.f, pzE = 0.f, pzO = 0.f;                     \
        float pnE = 0.f, pnO = 0.f;                                           \
        _Pragma("unroll")                                                     \
        for (int c = 0; c < 8; c++) {                                         \
            v4f hv = *(const v4f*)&(HIN)[16 * c + hb];                        \
            DOT4PK(prE, prO, hv, Wr[c])                                       \
            DOT4PK(pzE, pzO, hv, Wz[c])                                       \
            DOT4PK(pnE, pnO, hv, Wn[c])                                       \
        }                                                                     \
        float p0 = prE + prO;                                                 \
        float p1 = pzE + pzO;                                                 \
        float p2 = pnE + pnO;                                                 \
        p0 = bfly_fold4(p0);                                                  \
        p1 = bfly_fold4(p1);                                                  \
        p2 = bfly_fold4(p2);                                                  \
        const float r_ = sigmoid_f(gr + p0);                                  \
        const float z_ = sigmoid_f(gz + p1);                                  \
        const float n_ = tanh_f(gn + r_ * (p2 + bhn));                        \
        h_old = fmaf(z_, h_old - n_, n_);                                     \
        if (ks == 0) {                                                        \
            (HOUT)[hw] = h_old;                                               \
            if (STORE_H) *hp = h_old;                                         \
        }                                                                     \
        if (STORE_H) hp += H_;                                                \
        gr = gr2_; gz = gz2_; gn = gn2_;                                      \
        __syncthreads();                                                      \
    }

    for (int t = 0; t < T_; t += 2) {
        GRU_STEP(h2[0], h2[1])
        GRU_STEP(h2[1], h2[0])
    }
#undef GRU_STEP

    if (FINAL) {
        // h2[1] is dead after the loop's trailing barrier — reuse linearly.
        if (ks == 0) h2[1][jg] = fmaxf(h_old, 0.0f);   // relu(last hidden)
        __syncthreads();
        if (tid < 3) {
            float acc = fc_b[tid];
            const float* fw = fc_w + tid * H_;
#pragma unroll
            for (int k = 0; k < H_; k++) acc = fmaf(h2[1][k], fw[k], acc);
            out[b * 3 + tid] = acc;
        }
    }
}

// ---------------------------------------------------------------------------
extern "C" void kernel_launch(void* const* d_in, const int* in_sizes, int n_in,
                              void* d_out, int out_size, void* d_ws, size_t ws_size,
                              hipStream_t stream)
{
    const int*   x    = (const int*)  d_in[0];
    const float* emb  = (const float*)d_in[1];
    const float* W_ih = (const float*)d_in[2];  // [2,384,128]
    const float* W_hh = (const float*)d_in[3];  // [2,384,128]
    const float* b_ih = (const float*)d_in[4];  // [2,384]
    const float* b_hh = (const float*)d_in[5];  // [2,384]
    const float* fc_w = (const float*)d_in[6];  // [3,128]
    const float* fc_b = (const float*)d_in[7];  // [3]
    float* out = (float*)d_out;

    const int M = B_ * T_;                                   // 131072 rows
    const size_t gx_f32 = (size_t)M * G3_ * sizeof(float);   // 201.3 MB

    float* gx = (float*)d_ws;
    float* h1 = (float*)((char*)d_ws + gx_f32);              // 67.1 MB

    dim3 ggx(G3_ / TN, M / TM);   // (3, 1024)
    dim3 bgx(256);
    dim3 grec(B_), brec(512);

    hipLaunchKernelGGL((gx_gemm<true>), ggx, bgx, 0, stream,
                       nullptr, x, emb, W_ih, b_ih, b_hh, gx);
    hipLaunchKernelGGL((gru_rec<true, false>), grec, brec, 0, stream,
                       gx, W_hh, b_hh, h1, nullptr, nullptr, nullptr);
    hipLaunchKernelGGL((gx_gemm<false>), ggx, bgx, 0, stream,
                       h1, nullptr, nullptr, W_ih + G3_ * H_, b_ih + G3_,
                       b_hh + G3_, gx);
    hipLaunchKernelGGL((gru_rec<false, true>), grec, brec, 0, stream,
                       gx, W_hh + G3_ * H_, b_hh + G3_, nullptr, fc_w, fc_b, out);
}

// Round 8
// 826.281 us; speedup vs baseline: 1.2095x; 1.1099x over previous
//
#include <hip/hip_runtime.h>
#include <hip/hip_bf16.h>

#define B_   256
#define T_   512
#define H_   128
#define G3_  384

// ---- tiled GEMM config ----
#define TM   128
#define TN   128
#define TK   32
#define LDA  132

// log2(e) and 2*log2(e): gate pre-activations are pre-scaled so the serial
// recurrence uses raw v_exp_f32 (2^x) with no per-call *1.4427 mul.
#define LOG2E_F  1.4426950408889634f
#define LOG2E2_F 2.8853900817779268f

typedef float v4f __attribute__((ext_vector_type(4)));
typedef float v2f __attribute__((ext_vector_type(2)));

__device__ __forceinline__ float fast_rcp(float x) {
    return __builtin_amdgcn_rcpf(x);
}
__device__ __forceinline__ float exp2_raw(float x) {
    return __builtin_amdgcn_exp2f(x);   // v_exp_f32: 2^x
}

// Forced packed-f32 FMA: acc = a*b + acc (lane-wise on the 2-wide pair).
// "v" constraints force ARCH-VGPR residency of all operands at every use —
// the allocator can no longer park W in AGPRs (R12/R14: VGPR_Count=88 < 96
// = W was AGPR-parked; ~96 v_accvgpr_read copies/step were the unexplained
// instruction inflation). Also halves dot issue: 96 v_fmac -> 48 v_pk_fma.
__device__ __forceinline__ void pk_fma(v2f& acc, v2f a, v2f b) {
    asm("v_pk_fma_f32 %0, %1, %2, %0" : "+v"(acc) : "v"(a), "v"(b));
}

// Butterfly sum over each aligned 4-lane quad, pure DPP, result on ALL lanes.
__device__ __forceinline__ float bfly_fold4(float v) {
    int x;
    x = __builtin_amdgcn_update_dpp(0, __float_as_int(v), 0x0B1, 0xF, 0xF, true);
    v += __int_as_float(x);   // xor 1
    x = __builtin_amdgcn_update_dpp(0, __float_as_int(v), 0x04E, 0xF, 0xF, true);
    v += __int_as_float(x);   // xor 2
    return v;
}

// ---------------------------------------------------------------------------
// gx GEMM (R2 structure). R14: b_hh folded into bias for r/z regions.
// R15: epilogue pre-scales by log2e (r,z) / 2log2e (n) — uniform per block.
// ---------------------------------------------------------------------------
template<bool GATHER>
__global__ __launch_bounds__(256, 2)
void gx_gemm(const float* __restrict__ X,
             const int*   __restrict__ idx,
             const float* __restrict__ emb,
             const float* __restrict__ W,     // [384,128] row-major
             const float* __restrict__ bias,  // [384]  (b_ih)
             const float* __restrict__ bias2, // [384]  (b_hh; only n<256 used)
             float*       __restrict__ gx)    // [M,384]
{
    __shared__ __align__(16) float As[2][TK][LDA];
    __shared__ __align__(16) float Bs[2][TK][LDA];

    const int tid = threadIdx.x;
    const int tn  = tid & 15;
    const int tm  = tid >> 4;
    const int n0  = blockIdx.x * TN;
    const int m0  = blockIdx.y * TM;

    const int q  = tid & 7;
    const float* rowA[4];
    const float* rowB[4];
#pragma unroll
    for (int s = 0; s < 4; s++) {
        const int r = (tid >> 3) + 32 * s;
        rowA[s] = GATHER ? (emb + (size_t)idx[m0 + r] * H_)
                         : (X + (size_t)(m0 + r) * H_);
        rowB[s] = W + (size_t)(n0 + r) * H_;
    }

    float4 stA[4], stB[4];
    auto load_chunk = [&](int kc) {
#pragma unroll
        for (int s = 0; s < 4; s++) {
            stA[s] = *(const float4*)(rowA[s] + kc + q * 4);
            stB[s] = *(const float4*)(rowB[s] + kc + q * 4);
        }
    };
    auto store_chunk = [&](int buf) {
#pragma unroll
        for (int s = 0; s < 4; s++) {
            const int r = (tid >> 3) + 32 * s;
#pragma unroll
            for (int d = 0; d < 4; d++) {
                As[buf][q * 4 + d][r] = ((const float*)&stA[s])[d];
                Bs[buf][q * 4 + d][r] = ((const float*)&stB[s])[d];
            }
        }
    };

    float4 acc[2][2][4];
#pragma unroll
    for (int a = 0; a < 2; a++)
#pragma unroll
        for (int b = 0; b < 2; b++)
#pragma unroll
            for (int c = 0; c < 4; c++) acc[a][b][c] = make_float4(0.f, 0.f, 0.f, 0.f);

    load_chunk(0);
    store_chunk(0);
    __syncthreads();

    for (int c = 0; c < 4; c++) {
        if (c < 3) load_chunk((c + 1) * TK);
        const int buf = c & 1;
#pragma unroll 4
        for (int k = 0; k < TK; k++) {
            float4 a0 = *(const float4*)&As[buf][k][tm * 4];
            float4 a1 = *(const float4*)&As[buf][k][64 + tm * 4];
            float4 b0 = *(const float4*)&Bs[buf][k][tn * 4];
            float4 b1 = *(const float4*)&Bs[buf][k][64 + tn * 4];
            float4 av[2] = {a0, a1}, bv[2] = {b0, b1};
#pragma unroll
            for (int mg = 0; mg < 2; mg++)
#pragma unroll
                for (int mi = 0; mi < 4; mi++) {
                    const float am = ((const float*)&av[mg])[mi];
#pragma unroll
                    for (int ng = 0; ng < 2; ng++) {
                        acc[mg][ng][mi].x = fmaf(am, bv[ng].x, acc[mg][ng][mi].x);
                        acc[mg][ng][mi].y = fmaf(am, bv[ng].y, acc[mg][ng][mi].y);
                        acc[mg][ng][mi].z = fmaf(am, bv[ng].z, acc[mg][ng][mi].z);
                        acc[mg][ng][mi].w = fmaf(am, bv[ng].w, acc[mg][ng][mi].w);
                    }
                }
        }
        if (c < 3) {
            store_chunk(buf ^ 1);
            __syncthreads();
        }
    }

    float4 bb0 = *(const float4*)(bias + n0 + tn * 4);
    float4 bb1 = *(const float4*)(bias + n0 + 64 + tn * 4);
    if (n0 < 2 * H_) {   // r/z gate regions: fold hidden bias in here (uniform)
        const float4 c0 = *(const float4*)(bias2 + n0 + tn * 4);
        const float4 c1 = *(const float4*)(bias2 + n0 + 64 + tn * 4);
        bb0.x += c0.x; bb0.y += c0.y; bb0.z += c0.z; bb0.w += c0.w;
        bb1.x += c1.x; bb1.y += c1.y; bb1.z += c1.z; bb1.w += c1.w;
    }
    // exp2 pre-scale (uniform per block: r,z -> log2e; n -> 2log2e)
    const float esc = (n0 < 2 * H_) ? LOG2E_F : LOG2E2_F;
#pragma unroll
    for (int mg = 0; mg < 2; mg++)
#pragma unroll
        for (int mi = 0; mi < 4; mi++) {
            const int m = m0 + mg * 64 + tm * 4 + mi;
            float* dst = gx + (size_t)m * G3_ + n0;
            float4 v0 = acc[mg][0][mi];
            v0.x = (v0.x + bb0.x) * esc; v0.y = (v0.y + bb0.y) * esc;
            v0.z = (v0.z + bb0.z) * esc; v0.w = (v0.w + bb0.w) * esc;
            float4 v1 = acc[mg][1][mi];
            v1.x = (v1.x + bb1.x) * esc; v1.y = (v1.y + bb1.y) * esc;
            v1.z = (v1.z + bb1.z) * esc; v1.w = (v1.w + bb1.w) * esc;
            *(float4*)(dst + tn * 4) = v0;
            *(float4*)(dst + 64 + tn * 4) = v1;
        }
}

// ---------------------------------------------------------------------------
// GRU recurrence — R15: R12 structure (U=1, K=4) + forced v_pk_fma_f32 dots
// + exp2-prescaled gates.
//
// Thread (jg = tid>>2, ks = tid&3) owns unit jg, cols ks*32..+31. W fragment
// = 48 v2f (96 floats), every use is an inline-asm pk_fma with "v" operands
// -> arch-VGPR resident by construction. Gate pre-activations arrive
// pre-scaled (gx epilogue; W/bhn scaled at fragment load):
//   sigmoid(x) = rcp(1 + 2^(-xs)),  xs = x*log2e
//   tanh(x)    = 1 - 2*rcp(2^(xs) + 1),  xs = x*2log2e
// so the serial chain uses raw v_exp_f32 with a free input negate.
//
// h2 swizzle unchanged from R12 (measured conflict-free): h[j] at word
// sw(j)=16*((j>>2)&7)+4*(j>>5)+(j&3); reads at 16c+4ks.
// ---------------------------------------------------------------------------
template<bool STORE_H, bool FINAL>
__global__ __launch_bounds__(512)
__attribute__((amdgpu_waves_per_eu(2, 2)))
void gru_rec(const float* __restrict__ gx,   // [B,T,384] pre-scaled, r/z incl b_hh
             const float* __restrict__ Whh,  // [384,128]
             const float* __restrict__ bhh,  // [384]
             float*       __restrict__ hseq, // [B,T,128] if STORE_H
             const float* __restrict__ fc_w, // [3,128]  if FINAL
             const float* __restrict__ fc_b, // [3]      if FINAL
             float*       __restrict__ out)  // [B,3]    if FINAL
{
    __shared__ __align__(16) float h2[2][H_];   // double-buffered swizzled h

    const int tid = threadIdx.x;
    const int b   = blockIdx.x;
    const int jg  = tid >> 2;      // hidden unit 0..127
    const int ks  = tid & 3;       // k-slice 0..3 (32 cols each)

    // --- W_hh fragment: rows jg / jg+128 / jg+256, cols ks*32..+31,
    // as 16 v2f per gate, pre-scaled for the exp2 gate forms ---
    v2f Wr[16], Wz[16], Wn[16];
    {
        const v4f* wr = (const v4f*)(Whh + (size_t)(jg      ) * H_ + ks * 32);
        const v4f* wz = (const v4f*)(Whh + (size_t)(jg + 128) * H_ + ks * 32);
        const v4f* wn = (const v4f*)(Whh + (size_t)(jg + 256) * H_ + ks * 32);
#pragma unroll
        for (int c = 0; c < 8; c++) {
            v4f t;
            t = wr[c] * LOG2E_F;  Wr[2 * c] = t.lo; Wr[2 * c + 1] = t.hi;
            t = wz[c] * LOG2E_F;  Wz[2 * c] = t.lo; Wz[2 * c + 1] = t.hi;
            t = wn[c] * LOG2E2_F; Wn[2 * c] = t.lo; Wn[2 * c + 1] = t.hi;
        }
    }

    const float bhn = bhh[jg + 2 * H_] * LOG2E2_F;  // r,z biases folded into gx

    const float* gxb = gx + (size_t)b * T_ * G3_;
    float gr = gxb[jg], gz = gxb[jg + 128], gn = gxb[jg + 256];
    float h_old = 0.0f;

    if (tid < H_) h2[0][tid] = 0.0f;   // zeros are swizzle-invariant

    // write word for this unit: sw(jg)
    const int hw = ((jg >> 2) & 7) * 16 + (jg >> 5) * 4 + (jg & 3);
    const int hb = ks * 4;             // read base within each 16-word chunk

    // walked pointers (strength-reduced; no per-step mul / clamp)
    const float* gnx = gxb + G3_;
    float* hp = STORE_H ? (hseq + (size_t)b * T_ * H_ + jg) : nullptr;

    __syncthreads();

#define GRU_STEP(HIN, HOUT)                                                   \
    {                                                                         \
        const float gr2_ = gnx[jg];                                           \
        const float gz2_ = gnx[jg + 128];                                     \
        const float gn2_ = gnx[jg + 256];                                     \
        gnx += G3_;                                                           \
        v2f pr = {0.f, 0.f}, pz = {0.f, 0.f}, pn = {0.f, 0.f};                \
        _Pragma("unroll")                                                     \
        for (int c = 0; c < 8; c++) {                                         \
            v4f hv = *(const v4f*)&(HIN)[16 * c + hb];                        \
            v2f hlo = hv.lo, hhi = hv.hi;                                     \
            pk_fma(pr, hlo, Wr[2 * c]);  pk_fma(pr, hhi, Wr[2 * c + 1]);      \
            pk_fma(pz, hlo, Wz[2 * c]);  pk_fma(pz, hhi, Wz[2 * c + 1]);      \
            pk_fma(pn, hlo, Wn[2 * c]);  pk_fma(pn, hhi, Wn[2 * c + 1]);      \
        }                                                                     \
        const float p0 = bfly_fold4(pr.x + pr.y);                             \
        const float p1 = bfly_fold4(pz.x + pz.y);                             \
        const float p2 = bfly_fold4(pn.x + pn.y);                             \
        const float r_ = fast_rcp(1.0f + exp2_raw(-(gr + p0)));               \
        const float z_ = fast_rcp(1.0f + exp2_raw(-(gz + p1)));               \
        const float n_ = fmaf(-2.0f,                                          \
            fast_rcp(exp2_raw(gn + r_ * (p2 + bhn)) + 1.0f), 1.0f);           \
        h_old = fmaf(z_, h_old - n_, n_);                                     \
        if (ks == 0) {                                                        \
            (HOUT)[hw] = h_old;                                               \
            if (STORE_H) *hp = h_old;                                         \
        }                                                                     \
        if (STORE_H) hp += H_;                                                \
        gr = gr2_; gz = gz2_; gn = gn2_;                                      \
        __syncthreads();                                                      \
    }

    for (int t = 0; t < T_; t += 2) {
        GRU_STEP(h2[0], h2[1])
        GRU_STEP(h2[1], h2[0])
    }
#undef GRU_STEP

    if (FINAL) {
        // h2[1] is dead after the loop's trailing barrier — reuse linearly.
        if (ks == 0) h2[1][jg] = fmaxf(h_old, 0.0f);   // relu(last hidden)
        __syncthreads();
        if (tid < 3) {
            float acc = fc_b[tid];
            const float* fw = fc_w + tid * H_;
#pragma unroll
            for (int k = 0; k < H_; k++) acc = fmaf(h2[1][k], fw[k], acc);
            out[b * 3 + tid] = acc;
        }
    }
}

// ---------------------------------------------------------------------------
extern "C" void kernel_launch(void* const* d_in, const int* in_sizes, int n_in,
                              void* d_out, int out_size, void* d_ws, size_t ws_size,
                              hipStream_t stream)
{
    const int*   x    = (const int*)  d_in[0];
    const float* emb  = (const float*)d_in[1];
    const float* W_ih = (const float*)d_in[2];  // [2,384,128]
    const float* W_hh = (const float*)d_in[3];  // [2,384,128]
    const float* b_ih = (const float*)d_in[4];  // [2,384]
    const float* b_hh = (const float*)d_in[5];  // [2,384]
    const float* fc_w = (const float*)d_in[6];  // [3,128]
    const float* fc_b = (const float*)d_in[7];  // [3]
    float* out = (float*)d_out;

    const int M = B_ * T_;                                   // 131072 rows
    const size_t gx_f32 = (size_t)M * G3_ * sizeof(float);   // 201.3 MB

    float* gx = (float*)d_ws;
    float* h1 = (float*)((char*)d_ws + gx_f32);              // 67.1 MB

    dim3 ggx(G3_ / TN, M / TM);   // (3, 1024)
    dim3 bgx(256);
    dim3 grec(B_), brec(512);

    hipLaunchKernelGGL((gx_gemm<true>), ggx, bgx, 0, stream,
                       nullptr, x, emb, W_ih, b_ih, b_hh, gx);
    hipLaunchKernelGGL((gru_rec<true, false>), grec, brec, 0, stream,
                       gx, W_hh, b_hh, h1, nullptr, nullptr, nullptr);
    hipLaunchKernelGGL((gx_gemm<false>), ggx, bgx, 0, stream,
                       h1, nullptr, nullptr, W_ih + G3_ * H_, b_ih + G3_,
                       b_hh + G3_, gx);
    hipLaunchKernelGGL((gru_rec<false, true>), grec, brec, 0, stream,
                       gx, W_hh + G3_ * H_, b_hh + G3_, nullptr, fc_w, fc_b, out);
}